// Round 5
// baseline (184.460 us; speedup 1.0000x reference)
//
#include <hip/hip_runtime.h>

// Output = jacobi(X, Mask1, 100) — the multigrid sweeps in the reference are
// dead code for the returned value (grids[0] is never mutated).
//
// Trapezoidal temporal blocking, register-resident: 10 launches x 10 fused
// iterations. Patch = 8 tall x 4 wide per thread (halo exchange 6 B/cell vs
// 8 B/cell for 4x4 — LDS byte traffic is the binding resource). 128-thread
// blocks = 8x16 patches = 64x64 tile. LDS holds only per-patch edge strips
// (double-buffered, 1 barrier/iter). Tile edges compute bounded garbage that
// never reaches the central 44x44 output window (light-cone); the zeroed
// strip guard ring doubles as the true zero padding at domain boundaries.

#define W 1024
#define H 1024
#define TILE 64
#define TI 10                    // fused iterations per launch
#define OS (TILE - 2 * TI)       // 44 valid output per tile
#define NB 24                    // ceil(1024/44)
#define NLAUNCH 10               // NLAUNCH * TI = 100

// strip grids: 8 patch-rows x 16 patch-cols + guard ring
#define SRr 10
#define SRc 18
// strip ids: 0=T (top rows), 1=B (bottom rows), 2=L0,3=L1 (left col packed
// rows 0-3 / 4-7), 4=R0,5=R1 (right col packed)

__device__ __forceinline__ float2 ld2(const float* __restrict__ p, int gr, int gc) {
    // gc always even, W even -> pair entirely in or out of [0,W); 8B aligned
    if ((unsigned)gr < (unsigned)H && (unsigned)gc < (unsigned)W)
        return *(const float2*)&p[gr * W + gc];
    return make_float2(0.f, 0.f);
}

__device__ __forceinline__ float4 rowstep(const float4 up, const float4 ce,
                                          const float4 dn, const float lf,
                                          const float rt, const float4 m) {
    float4 s, n;
    s.x = (up.x + dn.x) + (lf   + ce.y);
    s.y = (up.y + dn.y) + (ce.x + ce.z);
    s.z = (up.z + dn.z) + (ce.y + ce.w);
    s.w = (up.w + dn.w) + (ce.z + rt);
    n.x = fmaf(m.x, fmaf(0.25f, s.x, -ce.x), ce.x);
    n.y = fmaf(m.y, fmaf(0.25f, s.y, -ce.y), ce.y);
    n.z = fmaf(m.z, fmaf(0.25f, s.z, -ce.z), ce.z);
    n.w = fmaf(m.w, fmaf(0.25f, s.w, -ce.w), ce.w);
    return n;
}

__device__ __forceinline__ void one_iter(
    const float4 (* __restrict__ rs)[SRr][SRc],
    float4 (* __restrict__ ws)[SRr][SRc],
    int pr, int pc, float4 (&c)[8], const float4 (&m)[8])
{
    const float4 th  = rs[1][pr    ][pc + 1];   // above patch's bottom row
    const float4 bh  = rs[0][pr + 2][pc + 1];   // below patch's top row
    const float4 lh0 = rs[4][pr + 1][pc    ];   // left patch's right col 0-3
    const float4 lh1 = rs[5][pr + 1][pc    ];   // left patch's right col 4-7
    const float4 rh0 = rs[2][pr + 1][pc + 2];   // right patch's left col 0-3
    const float4 rh1 = rs[3][pr + 1][pc + 2];   // right patch's left col 4-7

    float4 n[8];
    n[0] = rowstep(th,   c[0], c[1], lh0.x, rh0.x, m[0]);
    n[1] = rowstep(c[0], c[1], c[2], lh0.y, rh0.y, m[1]);
    n[2] = rowstep(c[1], c[2], c[3], lh0.z, rh0.z, m[2]);
    n[3] = rowstep(c[2], c[3], c[4], lh0.w, rh0.w, m[3]);
    n[4] = rowstep(c[3], c[4], c[5], lh1.x, rh1.x, m[4]);
    n[5] = rowstep(c[4], c[5], c[6], lh1.y, rh1.y, m[5]);
    n[6] = rowstep(c[5], c[6], c[7], lh1.z, rh1.z, m[6]);
    n[7] = rowstep(c[6], c[7], bh,   lh1.w, rh1.w, m[7]);

    ws[0][pr + 1][pc + 1] = n[0];
    ws[1][pr + 1][pc + 1] = n[7];
    ws[2][pr + 1][pc + 1] = make_float4(n[0].x, n[1].x, n[2].x, n[3].x);
    ws[3][pr + 1][pc + 1] = make_float4(n[4].x, n[5].x, n[6].x, n[7].x);
    ws[4][pr + 1][pc + 1] = make_float4(n[0].w, n[1].w, n[2].w, n[3].w);
    ws[5][pr + 1][pc + 1] = make_float4(n[4].w, n[5].w, n[6].w, n[7].w);

    __syncthreads();
    #pragma unroll
    for (int i = 0; i < 8; ++i) c[i] = n[i];
}

__global__ __launch_bounds__(128, 2) void jacobi_trap(
    const float* __restrict__ xin, const float* __restrict__ mask,
    float* __restrict__ xout)
{
    __shared__ float4 S[2][6][SRr][SRc];   // 34.6 KB

    const int tid = threadIdx.x;
    const int pr = tid >> 4, pc = tid & 15;
    const int gx0 = (int)blockIdx.x * OS - TI;
    const int gy0 = (int)blockIdx.y * OS - TI;
    const int gr0 = gy0 + pr * 8;
    const int gc0 = gx0 + pc * 4;           // always even

    // zero both strip buffers (guard ring must be 0; interior overwritten)
    {
        float4* flat = &S[0][0][0][0];
        const int tot = 2 * 6 * SRr * SRc;  // 2160
        #pragma unroll
        for (int k = 0; k < (tot + 127) / 128; ++k) {
            int idx = tid + k * 128;
            if (idx < tot) flat[idx] = make_float4(0.f, 0.f, 0.f, 0.f);
        }
    }

    // load 8x4 cells + mask into registers
    float4 c[8], m[8];
    #pragma unroll
    for (int i = 0; i < 8; ++i) {
        float2 a = ld2(xin, gr0 + i, gc0), b = ld2(xin, gr0 + i, gc0 + 2);
        c[i] = make_float4(a.x, a.y, b.x, b.y);
        float2 p = ld2(mask, gr0 + i, gc0), q = ld2(mask, gr0 + i, gc0 + 2);
        m[i] = make_float4(p.x, p.y, q.x, q.y);
    }

    __syncthreads();   // zero-fill visible before edge publish

    // publish initial edges into buffer 0
    S[0][0][pr + 1][pc + 1] = c[0];
    S[0][1][pr + 1][pc + 1] = c[7];
    S[0][2][pr + 1][pc + 1] = make_float4(c[0].x, c[1].x, c[2].x, c[3].x);
    S[0][3][pr + 1][pc + 1] = make_float4(c[4].x, c[5].x, c[6].x, c[7].x);
    S[0][4][pr + 1][pc + 1] = make_float4(c[0].w, c[1].w, c[2].w, c[3].w);
    S[0][5][pr + 1][pc + 1] = make_float4(c[4].w, c[5].w, c[6].w, c[7].w);
    __syncthreads();

    #pragma unroll 1
    for (int it = 0; it < TI / 2; ++it) {
        one_iter(S[0], S[1], pr, pc, c, m);
        one_iter(S[1], S[0], pr, pc, c, m);
    }

    // store central OS x OS window (float2 pairs; pair is in/out together)
    #pragma unroll
    for (int i = 0; i < 8; ++i) {
        int lr = pr * 8 + i;
        if (lr < TI || lr >= TILE - TI) continue;
        int gr = gy0 + lr;
        if ((unsigned)gr >= (unsigned)H) continue;
        int lc0 = pc * 4, gc = gx0 + lc0;
        if (lc0 >= TI && lc0 + 1 < TILE - TI && (unsigned)gc < (unsigned)W)
            *(float2*)&xout[gr * W + gc] = make_float2(c[i].x, c[i].y);
        int lc2 = lc0 + 2, gc2 = gc + 2;
        if (lc2 >= TI && lc2 + 1 < TILE - TI && (unsigned)gc2 < (unsigned)W)
            *(float2*)&xout[gr * W + gc2] = make_float2(c[i].z, c[i].w);
    }
}

extern "C" void kernel_launch(void* const* d_in, const int* in_sizes, int n_in,
                              void* d_out, int out_size, void* d_ws, size_t ws_size,
                              hipStream_t stream) {
    const float* X = (const float*)d_in[0];   // (1,1,1024,1024)
    const float* M = (const float*)d_in[1];   // Mask1
    float* out = (float*)d_out;
    float* ws  = (float*)d_ws;                // 4 MB ping buffer

    dim3 grid(NB, NB), block(128);
    // l=0: X->ws; alternate; l=9 (odd) -> out. The central-window union
    // covers the full domain, so ws/out are fully written before any read.
    const float* src = X;
    for (int l = 0; l < NLAUNCH; ++l) {
        float* dst = (l & 1) ? out : ws;
        jacobi_trap<<<grid, block, 0, stream>>>(src, M, dst);
        src = dst;
    }
}

// Round 6
// 138.261 us; speedup vs baseline: 1.3341x; 1.3341x over previous
//
#include <hip/hip_runtime.h>

// Output = jacobi(X, Mask1, 100) — the multigrid sweeps in the reference are
// dead code for the returned value (grids[0] is never mutated).
//
// Trapezoidal temporal blocking, register-resident: 10 launches x 10 fused
// iterations, 4x4 cells/thread in VGPRs, LDS = ONE set of edge strips
// (20.7 KB) with 2 barriers/iter. Small LDS -> 5-7 blocks/CU resident, so
// barrier convoys in one block are hidden by other blocks (round-5 showed
// the kernel is stall-bound, not LDS-byte-bound). Tile edges compute bounded
// garbage that never reaches the central 44x44 output window (light-cone);
// the zeroed strip guard ring doubles as zero padding at domain boundaries.

#define W 1024
#define H 1024
#define TILE 64
#define TI 10                    // fused iterations per launch
#define OS (TILE - 2 * TI)       // 44 valid output per tile
#define NB 24                    // ceil(1024/44)
#define NLAUNCH 10               // NLAUNCH * TI = 100
#define SR 18                    // strip dim: 16 patches + guard ring

#define S_T 0
#define S_B 1
#define S_L 2
#define S_R 3

__device__ __forceinline__ float2 ld2(const float* __restrict__ p, int gr, int gc) {
    // gc always even, W even -> pair entirely in or out of [0,W); 8B aligned
    if ((unsigned)gr < (unsigned)H && (unsigned)gc < (unsigned)W)
        return *(const float2*)&p[gr * W + gc];
    return make_float2(0.f, 0.f);
}

__device__ __forceinline__ float4 rowstep(const float4 up, const float4 ce,
                                          const float4 dn, const float lf,
                                          const float rt, const float4 m) {
    float4 s, n;
    s.x = (up.x + dn.x) + (lf   + ce.y);
    s.y = (up.y + dn.y) + (ce.x + ce.z);
    s.z = (up.z + dn.z) + (ce.y + ce.w);
    s.w = (up.w + dn.w) + (ce.z + rt);
    n.x = fmaf(m.x, fmaf(0.25f, s.x, -ce.x), ce.x);
    n.y = fmaf(m.y, fmaf(0.25f, s.y, -ce.y), ce.y);
    n.z = fmaf(m.z, fmaf(0.25f, s.z, -ce.z), ce.z);
    n.w = fmaf(m.w, fmaf(0.25f, s.w, -ce.w), ce.w);
    return n;
}

__global__ __launch_bounds__(256, 5) void jacobi_trap(
    const float* __restrict__ xin, const float* __restrict__ mask,
    float* __restrict__ xout)
{
    __shared__ float4 S[4][SR][SR];   // 20.7 KB, single-buffered

    const int tid = threadIdx.x;
    const int pr = tid >> 4, pc = tid & 15;
    const int gx0 = (int)blockIdx.x * OS - TI;
    const int gy0 = (int)blockIdx.y * OS - TI;
    const int gr0 = gy0 + pr * 4;
    const int gc0 = gx0 + pc * 4;               // always even

    // zero all strips (guard ring must be 0)
    {
        float4* flat = &S[0][0][0];
        const int tot = 4 * SR * SR;            // 1296
        #pragma unroll
        for (int k = 0; k < 6; ++k) {
            int idx = tid + k * 256;
            if (idx < tot) flat[idx] = make_float4(0.f, 0.f, 0.f, 0.f);
        }
    }

    // load 4x4 cells + mask into registers (float2 pairs, 8B-aligned)
    float4 c0, c1, c2, c3, m0, m1, m2, m3;
    {
        float4 cc[4], mm[4];
        #pragma unroll
        for (int i = 0; i < 4; ++i) {
            int gr = gr0 + i;
            float2 a = ld2(xin, gr, gc0), b = ld2(xin, gr, gc0 + 2);
            cc[i] = make_float4(a.x, a.y, b.x, b.y);
            float2 p = ld2(mask, gr, gc0), q = ld2(mask, gr, gc0 + 2);
            mm[i] = make_float4(p.x, p.y, q.x, q.y);
        }
        c0 = cc[0]; c1 = cc[1]; c2 = cc[2]; c3 = cc[3];
        m0 = mm[0]; m1 = mm[1]; m2 = mm[2]; m3 = mm[3];
    }

    __syncthreads();   // zero-fill visible before interior publish

    // publish initial edges
    S[S_T][pr + 1][pc + 1] = c0;
    S[S_B][pr + 1][pc + 1] = c3;
    S[S_L][pr + 1][pc + 1] = make_float4(c0.x, c1.x, c2.x, c3.x);
    S[S_R][pr + 1][pc + 1] = make_float4(c0.w, c1.w, c2.w, c3.w);
    __syncthreads();

    #pragma unroll 1
    for (int it = 0; it < TI; ++it) {
        // read halos of iteration `it`
        const float4 th = S[S_B][pr    ][pc + 1];
        const float4 bh = S[S_T][pr + 2][pc + 1];
        const float4 lh = S[S_R][pr + 1][pc    ];
        const float4 rh = S[S_L][pr + 1][pc + 2];
        __syncthreads();                         // all reads done

        const float4 n0 = rowstep(th, c0, c1, lh.x, rh.x, m0);
        const float4 n1 = rowstep(c0, c1, c2, lh.y, rh.y, m1);
        const float4 n2 = rowstep(c1, c2, c3, lh.z, rh.z, m2);
        const float4 n3 = rowstep(c2, c3, bh, lh.w, rh.w, m3);

        S[S_T][pr + 1][pc + 1] = n0;
        S[S_B][pr + 1][pc + 1] = n3;
        S[S_L][pr + 1][pc + 1] = make_float4(n0.x, n1.x, n2.x, n3.x);
        S[S_R][pr + 1][pc + 1] = make_float4(n0.w, n1.w, n2.w, n3.w);

        c0 = n0; c1 = n1; c2 = n2; c3 = n3;
        __syncthreads();                         // writes visible
    }

    // store central OS x OS window (float2 pairs; pair is in/out together)
    #pragma unroll
    for (int i = 0; i < 4; ++i) {
        int lr = pr * 4 + i;
        if (lr < TI || lr >= TILE - TI) continue;
        int gr = gy0 + lr;
        if ((unsigned)gr >= (unsigned)H) continue;
        const float4 ci = (i == 0) ? c0 : (i == 1) ? c1 : (i == 2) ? c2 : c3;
        int lc0 = pc * 4, gc = gx0 + lc0;
        if (lc0 >= TI && lc0 < TILE - TI && (unsigned)gc < (unsigned)W)
            *(float2*)&xout[gr * W + gc] = make_float2(ci.x, ci.y);
        int lc2 = lc0 + 2, gc2 = gc + 2;
        if (lc2 >= TI && lc2 < TILE - TI && (unsigned)gc2 < (unsigned)W)
            *(float2*)&xout[gr * W + gc2] = make_float2(ci.z, ci.w);
    }
}

extern "C" void kernel_launch(void* const* d_in, const int* in_sizes, int n_in,
                              void* d_out, int out_size, void* d_ws, size_t ws_size,
                              hipStream_t stream) {
    const float* X = (const float*)d_in[0];   // (1,1,1024,1024)
    const float* M = (const float*)d_in[1];   // Mask1
    float* out = (float*)d_out;
    float* ws  = (float*)d_ws;                // 4 MB ping buffer

    dim3 grid(NB, NB), block(256);
    // l=0: X->ws; alternate; l=9 (odd) -> out. The central-window union
    // covers the full domain, so ws/out are fully written before any read.
    const float* src = X;
    for (int l = 0; l < NLAUNCH; ++l) {
        float* dst = (l & 1) ? out : ws;
        jacobi_trap<<<grid, block, 0, stream>>>(src, M, dst);
        src = dst;
    }
}